// Round 3
// baseline (445.142 us; speedup 1.0000x reference)
//
#include <hip/hip_runtime.h>
#include <math.h>

#define BB 8
#define CC 256
#define HH 128
#define WW 128
#define HWP 16384          // 128*128
#define MH 512
#define MW 512
#define NPIX (BB*HWP)      // 131072
#define IQ 4096            // HWP/4 quads per image

// phase-2 tile geometry
#define TW 64
#define TH 4
#define IW 70
#define IH 10
#define PITCH 72

__device__ __forceinline__ void publish(unsigned* ctr) {
    __syncthreads();                       // all block writes ordered before release
    if (threadIdx.x == 0)
        __hip_atomic_fetch_add(ctr, 1u, __ATOMIC_RELEASE, __HIP_MEMORY_SCOPE_AGENT);
}

__device__ __forceinline__ void waitc(unsigned* ctr, unsigned tgt) {
    if (threadIdx.x == 0) {
        while (__hip_atomic_load(ctr, __ATOMIC_ACQUIRE, __HIP_MEMORY_SCOPE_AGENT) < tgt)
            __builtin_amdgcn_s_sleep(16);
    }
    __syncthreads();                       // acquire (L1/L2 inv) happens-before other lanes' reads
}

// ---------------------------------------------------------------------------
// Single fused kernel. 1024 blocks x 256 threads, >=4 blocks/CU guaranteed.
// Phase 1: even blocks -> antialias mask resize; odd blocks -> x channel
//          partial sum/max (float4).          publish ctr0 (target 1024)
// Phase 2: even blocks -> combine + 7x7 conv + sigmoid -> wprod.
//                                             publish ctr1 (target 512)
// Phase 3: every block -> 2 (b,c) planes: instance-norm + relu(5*), two-pass
//          over the 64KB plane (second pass L1/L2-resident).
// ---------------------------------------------------------------------------
__global__ __launch_bounds__(256, 4) void fused(const float* __restrict__ masks,
                                                const float* __restrict__ x,
                                                const float* __restrict__ cw,
                                                const float* __restrict__ gamma,
                                                const float* __restrict__ beta,
                                                float* __restrict__ out,
                                                unsigned* __restrict__ ctrs,
                                                float* __restrict__ wsb) {
    float* m_arr = wsb;                        // [NPIX]
    float* cs    = wsb + (size_t)NPIX;         // [4*NPIX]
    float* cm    = wsb + (size_t)5 * NPIX;     // [4*NPIX]
    float* wprod = wsb + (size_t)9 * NPIX;     // [NPIX]
    unsigned* ctr0 = ctrs;                     // phase-1 done count
    unsigned* ctr1 = ctrs + 32;                // phase-2 done count (separate line)

    __shared__ float w[147];
    __shared__ float pa[IH * PITCH], px[IH * PITCH], pm[IH * PITCH];
    __shared__ float ls[4], lss[4], smu, srs;

    const int bid = blockIdx.x, tid = threadIdx.x;
    const bool even = (bid & 1) == 0;
    const int e = bid >> 1;                    // 0..511 within parity class

    // ---------------- Phase 1 ----------------
    if (even) {
        // antialias 512->128 resize, branchless (clamped addr + zeroed weights)
        int t = e * 256 + tid;
        int j = t & 127, i = (t >> 7) & 127, b = t >> 14;
        const float Wt[8] = {1.f, 3.f, 5.f, 7.f, 7.f, 5.f, 3.f, 1.f};
        const float* mb = masks + (size_t)b * (MH * MW);
        int r0 = 4 * i - 2, c0 = 4 * j - 2;
        float cwgt[8]; int ccl[8];
        float sh = 0.f;
        #pragma unroll
        for (int q = 0; q < 8; q++) {
            int c = c0 + q;
            bool v = (unsigned)c < (unsigned)MW;
            cwgt[q] = v ? Wt[q] : 0.f;
            sh += cwgt[q];
            ccl[q] = min(max(c, 0), MW - 1);
        }
        float acc = 0.f, sv = 0.f;
        #pragma unroll
        for (int p = 0; p < 8; p++) {
            int r = r0 + p;
            bool v = (unsigned)r < (unsigned)MH;
            float wp = v ? Wt[p] : 0.f;
            sv += wp;
            const float* row = mb + (size_t)min(max(r, 0), MH - 1) * MW;
            float ra = 0.f;
            #pragma unroll
            for (int q = 0; q < 8; q++) ra += cwgt[q] * row[ccl[q]];
            acc += wp * ra;
        }
        m_arr[t] = acc / (sv * sh);
    } else {
        // x channel partial reduce: 64 channels, float4
        int chunk = e & 15, g = (e >> 4) & 3, b = e >> 6;
        int qi = chunk * 256 + tid;
        const float4* xb = (const float4*)x + ((size_t)(b * CC + g * 64)) * IQ + qi;
        float4 s = {0.f, 0.f, 0.f, 0.f};
        float4 mx = {-INFINITY, -INFINITY, -INFINITY, -INFINITY};
        #pragma unroll 8
        for (int c = 0; c < 64; c++) {
            float4 v = xb[(size_t)c * IQ];
            s.x += v.x; s.y += v.y; s.z += v.z; s.w += v.w;
            mx.x = fmaxf(mx.x, v.x); mx.y = fmaxf(mx.y, v.y);
            mx.z = fmaxf(mx.z, v.z); mx.w = fmaxf(mx.w, v.w);
        }
        size_t o = (size_t)g * (NPIX / 4) + (size_t)b * IQ + qi;
        ((float4*)cs)[o] = s;
        ((float4*)cm)[o] = mx;
    }
    publish(ctr0);

    // ---------------- Phase 2 (even blocks only) ----------------
    if (even) {
        waitc(ctr0, 1024);
        int bx = e & 1, by = (e >> 1) & 31, b = e >> 6;
        if (tid < 147) w[tid] = cw[tid];
        int ox = bx * TW - 3, oy = by * TH - 3;
        for (int idx = tid; idx < IW * IH; idx += 256) {
            int r = idx / IW, c = idx - r * IW;
            int gi = oy + r, gj = ox + c;
            float av = 0.f, mxv = 0.f, mv = 0.f;
            if ((unsigned)gi < (unsigned)HH && (unsigned)gj < (unsigned)WW) {
                int p = b * HWP + gi * WW + gj;
                mv = m_arr[p];
                float s = cs[p] + cs[p + NPIX] + cs[p + 2 * NPIX] + cs[p + 3 * NPIX];
                float mmx = fmaxf(fmaxf(cm[p], cm[p + NPIX]),
                                  fmaxf(cm[p + 2 * NPIX], cm[p + 3 * NPIX]));
                av = mv * s * (1.f / 256.f);
                mxv = mv * mmx;
            }
            pa[r * PITCH + c] = av;
            px[r * PITCH + c] = mxv;
            pm[r * PITCH + c] = mv;
        }
        __syncthreads();
        int col = tid & 63, r = tid >> 6;
        float acc = 0.f;
        #pragma unroll
        for (int di = 0; di < 7; di++) {
            #pragma unroll
            for (int dj = 0; dj < 7; dj++) {
                int li = (r + di) * PITCH + col + dj;
                acc += w[di * 7 + dj] * pa[li];
                acc += w[49 + di * 7 + dj] * px[li];
                acc += w[98 + di * 7 + dj] * pm[li];
            }
        }
        float at = 1.f / (1.f + expf(-acc));
        float res = pm[(r + 3) * PITCH + col + 3] * at;
        wprod[b * HWP + (by * TH + r) * WW + bx * TW + col] = res;
        publish(ctr1);
    }

    // ---------------- Phase 3 ----------------
    waitc(ctr1, 512);
    #pragma unroll
    for (int pl = 0; pl < 2; pl++) {
        int bc = bid + pl * 1024;          // b*256 + c
        int b = bc >> 8, c = bc & 255;
        const float4* xp = (const float4*)(x + (size_t)bc * HWP);
        const float4* wp = (const float4*)(wprod + (size_t)b * HWP);
        float s = 0.f, ss = 0.f;
        #pragma unroll 4
        for (int k = 0; k < 16; k++) {
            int idx = tid + k * 256;
            float4 xv = xp[idx];
            float4 wv = wp[idx];
            float a0 = xv.x * wv.x, a1 = xv.y * wv.y;
            float a2 = xv.z * wv.z, a3 = xv.w * wv.w;
            s += a0 + a1 + a2 + a3;
            ss += a0 * a0 + a1 * a1 + a2 * a2 + a3 * a3;
        }
        #pragma unroll
        for (int off = 32; off; off >>= 1) {
            s += __shfl_down(s, off, 64);
            ss += __shfl_down(ss, off, 64);
        }
        int wave = tid >> 6, lane = tid & 63;
        if (pl) __syncthreads();           // protect ls/lss reuse
        if (lane == 0) { ls[wave] = s; lss[wave] = ss; }
        __syncthreads();
        if (tid == 0) {
            float S = ls[0] + ls[1] + ls[2] + ls[3];
            float SS = lss[0] + lss[1] + lss[2] + lss[3];
            float mu = S * (1.f / HWP);
            float var = fmaxf(SS * (1.f / HWP) - mu * mu, 0.f);
            smu = mu;
            srs = rsqrtf(var + 1e-5f);
        }
        __syncthreads();
        float mu = smu;
        float g5 = 5.f * srs * gamma[c];
        float b5 = 5.f * beta[c];
        float4* op = (float4*)(out + (size_t)bc * HWP);
        #pragma unroll 4
        for (int k = 0; k < 16; k++) {
            int idx = tid + k * 256;
            float4 xv = xp[idx];           // L1/L2-resident re-read
            float4 wv = wp[idx];
            float4 r;
            r.x = fmaxf(fmaf(xv.x * wv.x - mu, g5, b5), 0.f);
            r.y = fmaxf(fmaf(xv.y * wv.y - mu, g5, b5), 0.f);
            r.z = fmaxf(fmaf(xv.z * wv.z - mu, g5, b5), 0.f);
            r.w = fmaxf(fmaf(xv.w * wv.w - mu, g5, b5), 0.f);
            op[idx] = r;
        }
    }
}

extern "C" void kernel_launch(void* const* d_in, const int* in_sizes, int n_in,
                              void* d_out, int out_size, void* d_ws, size_t ws_size,
                              hipStream_t stream) {
    const float* x      = (const float*)d_in[0];
    const float* masks  = (const float*)d_in[1];
    const float* conv_w = (const float*)d_in[2];
    const float* gamma  = (const float*)d_in[3];
    const float* beta   = (const float*)d_in[4];
    float* out = (float*)d_out;

    unsigned* ctrs = (unsigned*)d_ws;                  // 2 counters, separate lines
    float* wsb = (float*)d_ws + 128;                   // arrays start at +512 B

    hipMemsetAsync(d_ws, 0, 512, stream);              // zero counters (ws is poisoned)
    fused<<<1024, 256, 0, stream>>>(masks, x, conv_w, gamma, beta, out, ctrs, wsb);
}